// Round 1
// baseline (415.255 us; speedup 1.0000x reference)
//
#include <hip/hip_runtime.h>
#include <hip/hip_bf16.h>

// Static problem config (BEVFormer-base-ish, 50x50 BEV grid)
#define L_TOT   19560
#define NQ      2500
#define NCAMS   6
#define M_VAL   (NCAMS * L_TOT)   // 117360

typedef __attribute__((ext_vector_type(8))) short short8;
typedef __attribute__((ext_vector_type(4))) float f32x4;

__device__ __forceinline__ unsigned short f2bf(float x) {
  __hip_bfloat16 h = __float2bfloat16(x);
  return *reinterpret_cast<unsigned short*>(&h);
}
__device__ __forceinline__ unsigned int pack2bf(float lo, float hi) {
  return (unsigned int)f2bf(lo) | ((unsigned int)f2bf(hi) << 16);
}
__device__ __forceinline__ float bf_lo(unsigned int u) {
  return __uint_as_float(u << 16);
}
__device__ __forceinline__ float bf_hi(unsigned int u) {
  return __uint_as_float(u & 0xffff0000u);
}

__device__ __forceinline__ unsigned char canon_bool(const void* in, int i,
                                                    int mode) {
  if (mode == 1) return (unsigned char)(((const unsigned int*)in)[i] != 0u);
  if (mode == 2) return (unsigned char)(((const float*)in)[i] != 0.0f);
  return (unsigned char)(((const unsigned char*)in)[i] != 0);
}

// ---------------------------------------------------------------------------
// Parallel bev_mask canonicalizer (bool may arrive as u8 / i32 / f32).
// ---------------------------------------------------------------------------
__global__ void canon_mask_kernel(const void* __restrict__ in,
                                  unsigned char* __restrict__ outm,
                                  float* __restrict__ invcnt,
                                  const float* __restrict__ b_off,
                                  const float* __restrict__ b_attn,
                                  float* __restrict__ bcat) {
  __shared__ int notI, notF;
  if (threadIdx.x == 0) { notI = 0; notF = 0; }
  __syncthreads();
  const unsigned int* w = (const unsigned int*)in;
  for (int i = threadIdx.x; i < 3750; i += 256) {
    unsigned int x = w[i];
    if (x != 0u && x != 1u)          atomicOr(&notI, 1);
    if (x != 0u && x != 0x3f800000u) atomicOr(&notF, 1);
  }
  __syncthreads();
  const int mode = (notI == 0) ? 1 : ((notF == 0) ? 2 : 0);

  const int i = blockIdx.x * 256 + threadIdx.x;
  if (i < NCAMS * NQ) outm[i] = canon_bool(in, i, mode);

  if (blockIdx.x < 10) {
    const int q0 = blockIdx.x * 250;
    for (int q = q0 + threadIdx.x; q < q0 + 250; q += 256) {
      int cnt = 0;
#pragma unroll
      for (int c = 0; c < NCAMS; ++c) cnt += canon_bool(in, c * NQ + q, mode);
      invcnt[q] = 1.f / (float)max(cnt, 1);
    }
  } else if (blockIdx.x == 10) {
    for (int j = threadIdx.x; j < 768; j += 256)
      bcat[j] = (j < 512) ? b_off[j] : b_attn[j - 512];
  }
}

// ---------------------------------------------------------------------------
// Convert weights to bf16: W_value -> o0[65536]; [W_off;W_attn] -> o1[196608];
// W_out -> o2[65536].
// ---------------------------------------------------------------------------
__global__ void cvt_weights_kernel(const float* __restrict__ wv,
                                   const float* __restrict__ woff,
                                   const float* __restrict__ wattn,
                                   const float* __restrict__ wout,
                                   unsigned short* __restrict__ o0,
                                   unsigned short* __restrict__ o1,
                                   unsigned short* __restrict__ o2) {
  int i = blockIdx.x * 256 + threadIdx.x;
  if (i < 65536)        o0[i] = f2bf(wv[i]);
  else if (i < 196608)  o1[i - 65536] = f2bf(woff[i - 65536]);
  else if (i < 262144)  o1[131072 + (i - 196608)] = f2bf(wattn[i - 196608]);
  else if (i < 327680)  o2[i - 262144] = f2bf(wout[i - 262144]);
}

// ---------------------------------------------------------------------------
// Barrier-free streaming GEMM for the big value projection:
//   C[m, ch] = bf16( sum_k bf16(A[m,k]) * W[ch,k] + bias[ch] ),  K = N = 256.
// The entire W (256x256 bf16 = 128 KB) is LDS-resident per CU (one block of
// 512 threads per CU, loaded once, ONE __syncthreads total). A is streamed
// HBM -> VGPR in exact MFMA B-fragment layout (never touches LDS), so the
// main loop has NO barriers => no compiler-forced vmcnt(0) drains; loads stay
// in flight across MFMA phases (the structural fix for the 1.9 TB/s stall).
// 8 waves = 4 channel-groups (64 ch each) x 2 row-streams (64-row chunks,
// grid-stride over 1834 chunks). 2-deep register double-buffer (ra0/ra1,
// fully unrolled -> static indexing). W LDS rows are 512 B => 16-way bank
// conflict on ds_read_b128; fixed with byte ^= ((ch&7)<<4) XOR swizzle
// applied on BOTH write and read.
// ---------------------------------------------------------------------------
#define SG_ISSUE(B, CC, KK)                                                   \
  {                                                                           \
    _Pragma("unroll") for (int rt = 0; rt < 4; ++rt) {                        \
      const int row_ = (CC) * 64 + rt * 16 + fr;                              \
      const int rowc_ = row_ < M ? row_ : (M - 1); /* clamp: rows>=M unused */ \
      const float* p_ = A + (size_t)rowc_ * 256 + (KK) * 32 + fg * 8;         \
      ra##B[rt * 2]     = *(const float4*)p_;                                 \
      ra##B[rt * 2 + 1] = *(const float4*)(p_ + 4);                           \
    }                                                                         \
  }

#define SG_STEP(B, KT)                                                        \
  {                                                                           \
    short8 vf[4];                                                             \
    _Pragma("unroll") for (int rt = 0; rt < 4; ++rt) {                        \
      uint4 uu;                                                               \
      uu.x = pack2bf(ra##B[rt * 2].x,     ra##B[rt * 2].y);                   \
      uu.y = pack2bf(ra##B[rt * 2].z,     ra##B[rt * 2].w);                   \
      uu.z = pack2bf(ra##B[rt * 2 + 1].x, ra##B[rt * 2 + 1].y);               \
      uu.w = pack2bf(ra##B[rt * 2 + 1].z, ra##B[rt * 2 + 1].w);               \
      vf[rt] = *(short8*)&uu;                                                 \
    }                                                                         \
    _Pragma("unroll") for (int ct = 0; ct < 4; ++ct) {                        \
      const int wb_ = (chn[ct] * 512 + (KT) * 64 + fg * 16) ^ swz;            \
      const short8 wf_ = *(const short8*)((const char*)Ws + wb_);             \
      _Pragma("unroll") for (int rt = 0; rt < 4; ++rt)                        \
        acc[ct][rt] = __builtin_amdgcn_mfma_f32_16x16x32_bf16(                \
            wf_, vf[rt], acc[ct][rt], 0, 0, 0);                               \
    }                                                                         \
  }

__global__ __launch_bounds__(512, 2) void stream_gemm_kernel(
    const float* __restrict__ A, const unsigned short* __restrict__ Wbf,
    const float* __restrict__ bias, unsigned short* __restrict__ C,
    const int M) {
  __shared__ unsigned short Ws[256 * 256];  // 128 KB (gfx950 LDS = 160 KB)

  // ---- stage W into LDS once, XOR-swizzled ----
  {
    const int ch = threadIdx.x >> 1;  // 0..255 weight row (= channel)
    const int hf = threadIdx.x & 1;
    const uint4* src = (const uint4*)(Wbf + ch * 256 + hf * 128);
#pragma unroll
    for (int j = 0; j < 16; ++j) {
      const int byte = (ch * 512 + hf * 256 + j * 16) ^ ((ch & 7) << 4);
      *(uint4*)((char*)Ws + byte) = src[j];
    }
  }
  __syncthreads();  // the only barrier in this kernel

  const int wave = threadIdx.x >> 6;
  const int lane = threadIdx.x & 63;
  const int cg = wave & 3;   // channel group: 64 channels
  const int rs = wave >> 2;  // row stream: 0/1
  const int fr = lane & 15;
  const int fg = lane >> 4;
  const int swz = (fr & 7) << 4;  // (chn&7)<<4 == (fr&7)<<4 (16|64 are %8==0)
  int chn[4];
#pragma unroll
  for (int ct = 0; ct < 4; ++ct) chn[ct] = cg * 64 + ct * 16 + fr;

  float4 ra0[8], ra1[8];  // 2-deep pipeline staging, static-indexed only
  const int c0 = blockIdx.x * 2 + rs;  // stream id in [0,512)

  SG_ISSUE(0, c0, 0);
  for (int c = c0; c < 1834; c += 512) {  // 1834 = ceil(117360/64) chunks
    f32x4 acc[4][4] = {};
#pragma unroll
    for (int kp = 0; kp < 4; ++kp) {
      SG_ISSUE(1, c, kp * 2 + 1);   // next k-tile in flight across MFMAs
      SG_STEP(0, kp * 2);
      if (kp < 3) {
        SG_ISSUE(0, c, kp * 2 + 2);
      } else if (c + 512 < 1834) {
        SG_ISSUE(0, c + 512, 0);    // next chunk covered by epilogue stores
      }
      SG_STEP(1, kp * 2 + 1);
    }
    // epilogue: D layout -> data row = fr, channel = fg*4 + reg
#pragma unroll
    for (int ct = 0; ct < 4; ++ct) {
      const int ch = cg * 64 + ct * 16 + fg * 4;
      const float4 b4 = *(const float4*)&bias[ch];
#pragma unroll
      for (int rt = 0; rt < 4; ++rt) {
        const int m = c * 64 + rt * 16 + fr;
        if (m < M) {
          ushort4 u;
          u.x = f2bf(acc[ct][rt][0] + b4.x);
          u.y = f2bf(acc[ct][rt][1] + b4.y);
          u.z = f2bf(acc[ct][rt][2] + b4.z);
          u.w = f2bf(acc[ct][rt][3] + b4.w);
          *(ushort4*)(C + (size_t)m * 256 + ch) = u;
        }
      }
    }
  }
}

// ---------------------------------------------------------------------------
// bf16-MFMA GEMM with register double-buffer (used for the two small GEMMs).
// ---------------------------------------------------------------------------
template <bool BF16_OUT, bool HAS_A2, bool HAS_RES, bool HAS_SCALE>
__global__ __launch_bounds__(256, 3) void gemm_mfma_kernel(
    const float* __restrict__ A, const float* __restrict__ A2,
    const unsigned short* __restrict__ Wbf, const float* __restrict__ bias,
    const float* __restrict__ R, const float* __restrict__ rowscale,
    void* __restrict__ Cv, int M, int N) {
  __shared__ unsigned short As[128 * 40];  // data rows (bf16), pad to 40
  __shared__ unsigned short Bs[128 * 40];  // weight rows (channels)
  const int tid = threadIdx.x;
  const int m0 = blockIdx.x * 128;
  const int n0 = blockIdx.y * 128;
  const int wave = tid >> 6;
  const int lane = tid & 63;
  const int wr = (wave >> 1) * 64;  // row-block within tile
  const int wc = (wave & 1) * 64;   // channel-block within tile
  const int fr = lane & 15;
  const int fg = lane >> 4;

  // staging: thread -> (row 0..127, 16-element half)
  const int sr = tid >> 1;
  const int sc = (tid & 1) * 16;
  const bool a_ok = (m0 + sr) < M;
  const float* Ap = A + (size_t)(m0 + sr) * 256 + sc;
  const float* A2p = HAS_A2 ? (A2 + (size_t)(m0 + sr) * 256 + sc) : nullptr;
  const float ascale = (HAS_SCALE && a_ok) ? rowscale[m0 + sr] : 1.f;
  const unsigned short* Bp = Wbf + (size_t)(n0 + sr) * 256 + sc;
  unsigned short* asw = &As[sr * 40 + sc];
  unsigned short* bsw = &Bs[sr * 40 + sc];

  f32x4 acc[4][4] = {};  // [ct(channel)][rt(row)]

  // register staging buffers (raw, unprocessed)
  float4 ra[4], rt[4];
  uint4 rb0, rb1;

#define GEMM_ISSUE(KT)                                                     \
  {                                                                        \
    _Pragma("unroll") for (int j = 0; j < 4; ++j) {                        \
      ra[j] = a_ok ? *(const float4*)(Ap + (KT) * 32 + 4 * j)              \
                   : make_float4(0.f, 0.f, 0.f, 0.f);                      \
      if (HAS_A2)                                                          \
        rt[j] = a_ok ? *(const float4*)(A2p + (KT) * 32 + 4 * j)           \
                     : make_float4(0.f, 0.f, 0.f, 0.f);                    \
    }                                                                      \
    rb0 = *(const uint4*)(Bp + (KT) * 32);                                 \
    rb1 = *(const uint4*)(Bp + (KT) * 32 + 8);                             \
  }

  GEMM_ISSUE(0);

  for (int kt = 0; kt < 8; ++kt) {
    __syncthreads();  // all waves done reading LDS from previous iteration
    // STORE: process regs -> bf16 -> LDS
    {
      float4 s[4];
#pragma unroll
      for (int j = 0; j < 4; ++j) {
        s[j] = ra[j];
        if (HAS_A2) {
          s[j].x += rt[j].x; s[j].y += rt[j].y;
          s[j].z += rt[j].z; s[j].w += rt[j].w;
        }
        if (HAS_SCALE) {
          s[j].x *= ascale; s[j].y *= ascale;
          s[j].z *= ascale; s[j].w *= ascale;
        }
      }
      uint4 u0, u1;
      u0.x = pack2bf(s[0].x, s[0].y); u0.y = pack2bf(s[0].z, s[0].w);
      u0.z = pack2bf(s[1].x, s[1].y); u0.w = pack2bf(s[1].z, s[1].w);
      u1.x = pack2bf(s[2].x, s[2].y); u1.y = pack2bf(s[2].z, s[2].w);
      u1.z = pack2bf(s[3].x, s[3].y); u1.w = pack2bf(s[3].z, s[3].w);
      *(uint4*)asw = u0;
      *(uint4*)(asw + 8) = u1;
      *(uint4*)bsw = rb0;
      *(uint4*)(bsw + 8) = rb1;
    }
    __syncthreads();

    if (kt < 7) GEMM_ISSUE(kt + 1);  // in flight across the MFMA phase

    short8 wf[4], vf[4];
#pragma unroll
    for (int ct = 0; ct < 4; ++ct)
      wf[ct] = *(const short8*)&Bs[(wc + ct * 16 + fr) * 40 + fg * 8];
#pragma unroll
    for (int rt2 = 0; rt2 < 4; ++rt2)
      vf[rt2] = *(const short8*)&As[(wr + rt2 * 16 + fr) * 40 + fg * 8];
#pragma unroll
    for (int ct = 0; ct < 4; ++ct)
#pragma unroll
      for (int rt2 = 0; rt2 < 4; ++rt2)
        acc[ct][rt2] = __builtin_amdgcn_mfma_f32_16x16x32_bf16(
            wf[ct], vf[rt2], acc[ct][rt2], 0, 0, 0);
  }
#undef GEMM_ISSUE

  // Epilogue: D layout -> data row = fr, channel = fg*4 + reg
#pragma unroll
  for (int rt2 = 0; rt2 < 4; ++rt2) {
    const int m = m0 + wr + rt2 * 16 + fr;
    if (m >= M) continue;
#pragma unroll
    for (int ct = 0; ct < 4; ++ct) {
      const int ch = n0 + wc + ct * 16 + fg * 4;
      float o[4];
#pragma unroll
      for (int r = 0; r < 4; ++r) o[r] = acc[ct][rt2][r] + bias[ch + r];
      if (HAS_RES) {
        const float4 r4 = *(const float4*)&R[(size_t)m * N + ch];
        o[0] += r4.x; o[1] += r4.y; o[2] += r4.z; o[3] += r4.w;
      }
      if (BF16_OUT) {
        ushort4 u;
        u.x = f2bf(o[0]); u.y = f2bf(o[1]); u.z = f2bf(o[2]); u.w = f2bf(o[3]);
        *(ushort4*)((unsigned short*)Cv + (size_t)m * N + ch) = u;
      } else {
        float4 of; of.x = o[0]; of.y = o[1]; of.z = o[2]; of.w = o[3];
        *(float4*)((float*)Cv + (size_t)m * N + ch) = of;
      }
    }
  }
}

// ---------------------------------------------------------------------------
// Sampler v3: one block per (cam, query) pair; 256 threads = 2 sample-groups
// of 128 threads (2 channels each).
// ---------------------------------------------------------------------------
__global__ __launch_bounds__(256) void sampler3_kernel(
    const unsigned short* __restrict__ v, const float* __restrict__ offlog,
    const float* __restrict__ ref, const unsigned char* __restrict__ mask,
    float* __restrict__ slots) {
  const int pair = blockIdx.x;                 // c * NQ + q
  if (!mask[pair]) return;
  const int c = pair / NQ;
  const int q = pair - c * NQ;
  const int t = threadIdx.x;                   // 0..255

  __shared__ float sx[256], sy[256], sw[256];
  {
    const float Wl[4] = {160.f, 80.f, 40.f, 20.f};
    const float Hl[4] = {92.f, 46.f, 23.f, 12.f};
    const int combo = t;                       // (h,l,p): h=combo>>5
    const int l = (combo >> 3) & 3;
    const int p = combo & 7;
    const int z = p & 3;                       // NP//NZ x NZ reshape
    const float2 rz = ((const float2*)ref)[q * 4 + z];
    const float2 o2 = ((const float2*)offlog)[(size_t)q * 384 + combo];
    sx[combo] = rz.x * Wl[l] + o2.x - 0.5f;
    sy[combo] = rz.y * Hl[l] + o2.y - 0.5f;
    float lg = offlog[(size_t)q * 768 + 512 + combo];
    float mx = lg;
    for (int s = 16; s; s >>= 1) mx = fmaxf(mx, __shfl_xor(mx, s, 32));
    float e = __expf(lg - mx);
    float sm = e;
    for (int s = 16; s; s >>= 1) sm += __shfl_xor(sm, s, 32);
    sw[combo] = e / sm;
  }
  __syncthreads();

  const int WW[4] = {160, 80, 40, 20};
  const int HH[4] = {92, 46, 23, 12};
  const int LS[4] = {0, 14720, 18400, 19320};

  const int tt = t & 127;                      // channel pair
  const int grp = t >> 7;                      // sample group
  const unsigned int* vc =
      (const unsigned int*)(v + (size_t)c * (L_TOT * 256)) + tt;
  const int cbase = (tt >> 4) * 32;
  const int sbase = grp * 16;
  float acc0 = 0.f, acc1 = 0.f;

#pragma unroll
  for (int j = 0; j < 16; ++j) {
    const int s = sbase + j;
    const int lvl = s >> 3;
    const int combo = cbase + s;
    const float x = sx[combo], y = sy[combo], w = sw[combo];
    const float fx0 = floorf(x), fy0 = floorf(y);
    const float fx = x - fx0, fy = y - fy0;
    const int x0 = (int)fx0, y0 = (int)fy0;
    const int Wi = WW[lvl], Hi = HH[lvl];
    const int x0c = min(max(x0, 0), Wi - 1);
    const int x1c = min(max(x0 + 1, 0), Wi - 1);
    const int y0c = min(max(y0, 0), Hi - 1);
    const int y1c = min(max(y0 + 1, 0), Hi - 1);
    const float vx0 = (x0 >= 0 && x0 < Wi) ? 1.f : 0.f;
    const float vx1 = (x0 + 1 >= 0 && x0 + 1 < Wi) ? 1.f : 0.f;
    const float vy0 = (y0 >= 0 && y0 < Hi) ? 1.f : 0.f;
    const float vy1 = (y0 + 1 >= 0 && y0 + 1 < Hi) ? 1.f : 0.f;
    const unsigned int* vl = vc + (size_t)LS[lvl] * 128;
    const unsigned int u00 = vl[(y0c * Wi + x0c) * 128];
    const unsigned int u01 = vl[(y0c * Wi + x1c) * 128];
    const unsigned int u10 = vl[(y1c * Wi + x0c) * 128];
    const unsigned int u11 = vl[(y1c * Wi + x1c) * 128];
    const float w00 = (1.f - fx) * (1.f - fy) * vx0 * vy0 * w;
    const float w01 = fx * (1.f - fy) * vx1 * vy0 * w;
    const float w10 = (1.f - fx) * fy * vx0 * vy1 * w;
    const float w11 = fx * fy * vx1 * vy1 * w;
    acc0 += w00 * bf_lo(u00) + w01 * bf_lo(u01) +
            w10 * bf_lo(u10) + w11 * bf_lo(u11);
    acc1 += w00 * bf_hi(u00) + w01 * bf_hi(u01) +
            w10 * bf_hi(u10) + w11 * bf_hi(u11);
  }
  atomicAdd(&slots[q * 256 + tt * 2], acc0);
  atomicAdd(&slots[q * 256 + tt * 2 + 1], acc1);
}

// ---------------------------------------------------------------------------
extern "C" void kernel_launch(void* const* d_in, const int* in_sizes, int n_in,
                              void* d_out, int out_size, void* d_ws,
                              size_t ws_size, hipStream_t stream) {
  const float* query  = (const float*)d_in[0];
  // d_in[1] = key : unused by the reference forward
  const float* value  = (const float*)d_in[2];
  const float* qpos   = (const float*)d_in[3];
  const float* refpts = (const float*)d_in[4];
  const void*  bmask  = d_in[5];
  const float* W_value = (const float*)d_in[8];
  const float* b_value = (const float*)d_in[9];
  const float* W_off   = (const float*)d_in[10];
  const float* b_off   = (const float*)d_in[11];
  const float* W_attn  = (const float*)d_in[12];
  const float* b_attn  = (const float*)d_in[13];
  const float* W_out   = (const float*)d_in[14];
  const float* b_out   = (const float*)d_in[15];
  float* out = (float*)d_out;

  // workspace layout (~71 MB)
  unsigned short* ws_v = (unsigned short*)d_ws;                    // M_VAL*256 bf16
  unsigned short* ws_wv   = ws_v + (size_t)M_VAL * 256;            // 65536
  unsigned short* ws_wq   = ws_wv + 65536;                         // 196608
  unsigned short* ws_wout = ws_wq + 196608;                        // 65536
  float* ws_offlog = (float*)(ws_wout + 65536);                    // NQ*768
  float* ws_slots  = ws_offlog + (size_t)NQ * 768;                 // NQ*256
  float* ws_invcnt = ws_slots + (size_t)NQ * 256;                  // NQ
  float* ws_bcat   = ws_invcnt + NQ;                               // 768
  unsigned char* ws_mask = (unsigned char*)(ws_bcat + 768);        // NCAMS*NQ

  canon_mask_kernel<<<60, 256, 0, stream>>>(bmask, ws_mask, ws_invcnt,
                                            b_off, b_attn, ws_bcat);
  cvt_weights_kernel<<<1280, 256, 0, stream>>>(
      W_value, W_off, W_attn, W_out, ws_wv, ws_wq, ws_wout);
  hipMemsetAsync(ws_slots, 0, (size_t)NQ * 256 * sizeof(float), stream);

  // v = value @ W_value^T + b_value   (117360 x 256), bf16 out
  // barrier-free streaming GEMM: 1 block/CU, W LDS-resident, A HBM->reg.
  stream_gemm_kernel<<<256, 512, 0, stream>>>(value, ws_wv, b_value, ws_v,
                                              M_VAL);

  // [off | logits] = (q+qpos) @ [W_off;W_attn]^T + bcat   (2500 x 768)
  gemm_mfma_kernel<false, true, false, false><<<dim3(20, 6), 256, 0, stream>>>(
      query, qpos, ws_wq, ws_bcat, nullptr, nullptr, (void*)ws_offlog,
      NQ, 768);

  sampler3_kernel<<<NCAMS * NQ, 256, 0, stream>>>(
      ws_v, ws_offlog, refpts, ws_mask, ws_slots);

  // out = (slots/cnt) @ W_out^T + b_out + query   (2500 x 256)
  gemm_mfma_kernel<false, false, true, true><<<dim3(20, 2), 256, 0, stream>>>(
      ws_slots, nullptr, ws_wout, b_out, query, ws_invcnt, (void*)out,
      NQ, 256);
}